// Round 6
// baseline (995.786 us; speedup 1.0000x reference)
//
#include <hip/hip_runtime.h>
#include <math.h>

// Min-sum BP LDPC decoder, LDS-resident messages in VAR-ORDER layout.
// msg[4v..4v+3] = var v's 4 edge messages -> var phase & epilogue are aligned
// b128 LDS ops (conflict-free). Check phase addresses its edges via positions
// cached in REGISTERS (packed 2x16b, 7 ints per check, d<=14), loaded once
// from posbs[] (positions renumbered contiguously in degree-sorted check
// order). Zero global loads inside the 10-iteration loop.
//
// R6 fix vs R5 (still spilled: VGPR stuck at 64, 42/103 MB scratch traffic):
//  - amdgpu_waves_per_eu(4,4): backend's occupancy target was 8 waves/EU
//    (64-VGPR cap) -> pressure spill. A 1024-thr block hard-caps at 128 VGPR
//    (16 waves resident); tell the backend 4 waves/EU explicitly.
//  - single check arm (check_reg<14> only): the dual <8>/<14> ladder kept two
//    x[]/p[] transient sets alive in divergent arms. Degrees are wave-uniform
//    (sorted), so early exec-mask exit makes one arm cheap.
//  - var phase single batch of 8 b128 loads (MLP; affordable at 128 regs).

#define BLOCK 1024
#define NV    8192          // N variables
#define MC    4096          // M checks
#define NE    32768         // E edges (N * DV, DV=4)
#define VPT   (NV / BLOCK)  // 8 vars per thread
#define CPT   (MC / BLOCK)  // 4 checks per thread (consecutive sorted)
#define NITER 10
#define ALPHA 0.8f
#define CLAMP 20.0f
#define DCAP  14            // register-cache degree cap (7 packed ints/check)

// ws layout (ints), offsets multiple of 64 for alignment:
#define WS_POSW  0                       // [NE]   word pos of edge e (orig id)
#define WS_ST2   (NE)                    // [MC+1] edge prefix, sorted order
#define WS_SC    (NE + MC + 64)          // [MC]   orig check idx per sorted slot
#define WS_POSBS (NE + 2*MC + 128)       // [NE]   positions, sorted-contiguous
#define WS_PAD   (2*NE + 2*MC + 128)     // [1]    word pos of edge 0

// ---------------- setup: sort checks by degree, build posbs ----------------
__global__ __launch_bounds__(BLOCK)
void setup_all(const float* __restrict__ check_mask,
               const int*   __restrict__ check_adj,
               const int*   __restrict__ var_adj,
               int max_dc, int* __restrict__ ws)
{
    __shared__ int ldeg[MC], lcst[MC], lso[MC];   // 48 KB
    __shared__ int part[BLOCK];
    __shared__ int hist[64], hbase[64];
    const int t = threadIdx.x;
    if (t < 64) hist[t] = 0;

    // posw: var v's j-th edge (ascending edge id = var_adj row order) lives at
    // var-order word 4v+j. Slot order preserves the reference's f32 sum order.
#pragma unroll
    for (int k = 0; k < VPT; ++k) {
        const int v = t + k * BLOCK;
        const int4 a = ((const int4*)var_adj)[v];
        ws[WS_POSW + a.x] = 4 * v + 0;
        ws[WS_POSW + a.y] = 4 * v + 1;
        ws[WS_POSW + a.z] = 4 * v + 2;
        ws[WS_POSW + a.w] = 4 * v + 3;
    }
    __syncthreads();
#pragma unroll
    for (int k = 0; k < CPT; ++k) {
        const int c = t + k * BLOCK;
        int d = 0;
        for (int j = 0; j < max_dc; ++j)
            d += (check_mask[(size_t)c * max_dc + j] != 0.0f) ? 1 : 0;
        ldeg[c] = d;
        lcst[c] = check_adj[(size_t)c * max_dc];  // row start (edges check-sorted)
        atomicAdd(&hist[d & 63], 1);
    }
    __syncthreads();
    if (t == 0) { int s = 0; for (int i = 0; i < 64; ++i) { hbase[i] = s; s += hist[i]; } }
    __syncthreads();
#pragma unroll
    for (int k = 0; k < CPT; ++k) {
        const int c = t + k * BLOCK;
        const int pos = atomicAdd(&hbase[ldeg[c] & 63], 1);
        lso[pos] = c;
    }
    __syncthreads();

    // prefix-sum sorted degrees (4 consecutive per thread + block scan)
    int sd[CPT]; int mysum = 0;
#pragma unroll
    for (int k = 0; k < CPT; ++k) { sd[k] = ldeg[lso[CPT * t + k]]; mysum += sd[k]; }
    part[t] = mysum; __syncthreads();
    for (int ofs = 1; ofs < BLOCK; ofs <<= 1) {
        const int v = (t >= ofs) ? part[t - ofs] : 0; __syncthreads();
        part[t] += v; __syncthreads();
    }
    int run = part[t] - mysum;   // exclusive prefix

#pragma unroll
    for (int k = 0; k < CPT; ++k) {
        const int i = CPT * t + k;
        const int c = lso[i];
        ws[WS_ST2 + i] = run;
        ws[WS_SC + i]  = c;
        const int cst = lcst[c];
        for (int j = 0; j < sd[k]; ++j)
            ws[WS_POSBS + run + j] = ws[WS_POSW + cst + j];
        run += sd[k];
    }
    if (t == BLOCK - 1) ws[WS_ST2 + MC] = run;
    if (t == 0)         ws[WS_PAD] = ws[WS_POSW + 0];
}

// Register-cached check update: positions packed 2x16b in pkc[7].
// ALL pk indices are compile-time static (j from unrolled loops only).
// Degrees are wave-uniform (sorted), so the per-lane break costs ~nothing.
template<int DMAX>
__device__ __forceinline__ void check_reg(float* __restrict__ msg,
                                          const int* pkc, int d,
                                          unsigned sb31, float pad)
{
    int p[DMAX]; float x[DMAX];
#pragma unroll
    for (int j = 0; j < DMAX; ++j)
        p[j] = (pkc[j >> 1] >> ((j & 1) * 16)) & 0xffff;
#pragma unroll
    for (int j = 0; j < DMAX; ++j) { if (j >= d) break; x[j] = msg[p[j]]; }

    float min1 = pad, min2 = pad;
    unsigned par = 0;
#pragma unroll
    for (int j = 0; j < DMAX; ++j) {
        if (j >= d) break;
        par ^= __float_as_uint(x[j]);               // MSB = sign parity
        const float a = fabsf(x[j]);
        min2 = fminf(min2, fmaxf(min1, a));         // two smallest, dup-exact
        min1 = fminf(min1, a);
    }
    const unsigned tb = sb31 ^ (par & 0x80000000u);
#pragma unroll
    for (int j = 0; j < DMAX; ++j) {
        if (j >= d) break;
        const float a = fabsf(x[j]);
        const float m = (fabsf(a - min1) < 1e-9f) ? min2 : min1;  // ref tolerance
        const unsigned sm = tb ^ (__float_as_uint(x[j]) & 0x80000000u);
        msg[p[j]] = __uint_as_float(__float_as_uint(ALPHA * m) ^ sm);
    }
}

// Fallback for d > DCAP (rare, ~1.2% of checks): batched global posbs reads.
__device__ __forceinline__ void check_glb(float* __restrict__ msg,
                                          const int* __restrict__ pp, int d,
                                          unsigned sb31, float pad)
{
    float min1 = pad, min2 = pad;
    unsigned par = 0;
    for (int j = 0; j < d; ++j) {
        const float xx = msg[pp[j]];
        par ^= __float_as_uint(xx);
        const float a = fabsf(xx);
        min2 = fminf(min2, fmaxf(min1, a));
        min1 = fminf(min1, a);
    }
    const unsigned tb = sb31 ^ (par & 0x80000000u);
    for (int j = 0; j < d; ++j) {
        const int   p  = pp[j];
        const float xx = msg[p];
        const float a  = fabsf(xx);
        const float m  = (fabsf(a - min1) < 1e-9f) ? min2 : min1;
        const unsigned sm = tb ^ (__float_as_uint(xx) & 0x80000000u);
        msg[p] = __uint_as_float(__float_as_uint(ALPHA * m) ^ sm);
    }
}

// LDS (128 KB) caps at 1 block/CU = 16 waves = 4 waves/EU. Tell the backend
// that IS the target so it may use the full 128-VGPR budget (default heuristic
// targeted 8 waves/EU -> 64-VGPR cap -> scratch spill, R4/R5).
__global__ __attribute__((amdgpu_waves_per_eu(4, 4))) __launch_bounds__(BLOCK)
void bp_decode(const float* __restrict__ syndrome,    // (B, M)
               const float* __restrict__ llr_g,       // (B, N)
               const int*   __restrict__ ws,
               float* __restrict__ out,               // marginals | hard | converged
               int B)
{
    __shared__ float msg[NE];   // 128 KB, var-order; ctv <-> vtc in place
    __shared__ float sh_pad;
    __shared__ int   mism;

    const int b = blockIdx.x;
    const int t = threadIdx.x;

#pragma unroll
    for (int k = 0; k < VPT; ++k)                     // ctv0 = 0
        ((float4*)msg)[t + k * BLOCK] = make_float4(0.f, 0.f, 0.f, 0.f);

    float llr[VPT];
#pragma unroll
    for (int k = 0; k < VPT; ++k)
        llr[k] = llr_g[(size_t)b * NV + t + k * BLOCK];

    const int pos0 = ws[WS_PAD];         // edge 0's word position
    const int v0   = pos0 >> 2;
    const int s0   = pos0 & 3;

    // my 4 consecutive degree-sorted checks
    const int4 s2a = *(const int4*)(ws + WS_ST2 + CPT * t);
    const int  s2e = ws[WS_ST2 + CPT * t + CPT];
    int st[CPT]  = { s2a.x, s2a.y, s2a.z, s2a.w };
    int deg[CPT] = { s2a.y - s2a.x, s2a.z - s2a.y, s2a.w - s2a.z, s2e - s2a.w };
    int dmax = 0;
#pragma unroll
    for (int k = 0; k < CPT; ++k) dmax = max(dmax, deg[k]);
    unsigned sb31[CPT];
#pragma unroll
    for (int k = 0; k < CPT; ++k) {
        const int c = ws[WS_SC + CPT * t + k];
        sb31[k] = (syndrome[(size_t)b * MC + c] > 0.5f) ? 0x80000000u : 0u;
    }
    const int* __restrict__ posbs = ws + WS_POSBS;
    const bool cached = (dmax <= DCAP);

    int pk[CPT * 7];
#pragma unroll
    for (int k = 0; k < CPT; ++k) {
        const int base = st[k];
        const int d    = cached ? deg[k] : 0;
#pragma unroll
        for (int jj = 0; jj < 7; ++jj) {
            const int j0 = 2 * jj, j1 = 2 * jj + 1;
            const int lo = (j0 < d) ? posbs[base + j0] : 0;
            const int hi = (j1 < d) ? posbs[base + j1] : 0;
            pk[k * 7 + jj] = lo | (hi << 16);
        }
    }
    __syncthreads();

    for (int it = 0; it < NITER; ++it) {
        // ---- variable phase: batch-issue all 8 b128 reads, compute, store ----
        float4 f[VPT];
#pragma unroll
        for (int k = 0; k < VPT; ++k) f[k] = ((const float4*)msg)[t + k * BLOCK];
#pragma unroll
        for (int k = 0; k < VPT; ++k) {
            const int v = t + k * BLOCK;
            const float tot  = ((f[k].x + f[k].y) + f[k].z) + f[k].w;  // ref order
            const float base = llr[k] + tot;
            float4 o;
            o.x = fminf(fmaxf(base - f[k].x, -CLAMP), CLAMP);
            o.y = fminf(fmaxf(base - f[k].y, -CLAMP), CLAMP);
            o.z = fminf(fmaxf(base - f[k].z, -CLAMP), CLAMP);
            o.w = fminf(fmaxf(base - f[k].w, -CLAMP), CLAMP);
            if (v == v0) {   // reference's pad = |vtc[edge0]| + 1e6
                float vt = o.x;
                if (s0 == 1) vt = o.y; else if (s0 == 2) vt = o.z; else if (s0 == 3) vt = o.w;
                sh_pad = fabsf(vt) + 1.0e6f;
            }
            ((float4*)msg)[v] = o;
        }
        __syncthreads();
        const float pad = sh_pad;

        // ---- check phase: register-cached positions, scattered b32 ----
        if (cached) {
#pragma unroll
            for (int k = 0; k < CPT; ++k)
                check_reg<DCAP>(msg, pk + k * 7, deg[k], sb31[k], pad);
        } else {
#pragma unroll
            for (int k = 0; k < CPT; ++k)
                check_glb(msg, posbs + st[k], deg[k], sb31[k], pad);
        }
        __syncthreads();
    }

    // ---- finale: marginals, hard decisions, convergence ----
    float marg[VPT], hard[VPT];
    {
        float4 f[VPT];
#pragma unroll
        for (int k = 0; k < VPT; ++k) f[k] = ((const float4*)msg)[t + k * BLOCK];
#pragma unroll
        for (int k = 0; k < VPT; ++k) {
            const float tot = ((f[k].x + f[k].y) + f[k].z) + f[k].w;
            const float tl  = llr[k] + tot;
            const float mg  = 1.0f / (1.0f + expf(tl));   // sigmoid(-tl)
            marg[k] = mg;
            hard[k] = (mg > 0.5f) ? 1.0f : 0.0f;
        }
    }
    if (t == 0) mism = 0;
    __syncthreads();   // all ctv reads done; mism initialized

    const size_t BN = (size_t)B * NV;
#pragma unroll
    for (int k = 0; k < VPT; ++k) {
        const int v = t + k * BLOCK;
        out[(size_t)b * NV + v]      = marg[k];        // output 0: marginals
        out[BN + (size_t)b * NV + v] = hard[k];        // output 1: hard_decision
        const float h = hard[k];
        ((float4*)msg)[v] = make_float4(h, h, h, h);   // hard bit to all slots
    }
    __syncthreads();

    // syn_hat parity per check; STATIC bound + break so pk indexing stays
    // static (the R3 spill bug was a runtime-bound loop right here).
#pragma unroll
    for (int k = 0; k < CPT; ++k) {
        int par = 0;
        if (cached) {
            const int* pkc = pk + k * 7;
#pragma unroll
            for (int j = 0; j < DCAP; ++j) {
                if (j >= deg[k]) break;
                const int p = (pkc[j >> 1] >> ((j & 1) * 16)) & 0xffff;
                par ^= (msg[p] != 0.0f) ? 1 : 0;
            }
        } else {
            const int* pp = posbs + st[k];
            for (int j = 0; j < deg[k]; ++j)
                par ^= (msg[pp[j]] != 0.0f) ? 1 : 0;
        }
        if ((par != 0) != (sb31[k] != 0u)) mism = 1;   // benign race
    }
    __syncthreads();
    if (t == 0) out[2 * BN + b] = mism ? 0.0f : 1.0f;  // output 2: converged
}

extern "C" void kernel_launch(void* const* d_in, const int* in_sizes, int n_in,
                              void* d_out, int out_size, void* d_ws, size_t ws_size,
                              hipStream_t stream) {
    const float* syndrome   = (const float*)d_in[0];
    const float* llr        = (const float*)d_in[1];
    const int*   var_adj    = (const int*)d_in[2];
    // d_in[3] var_adj_mask: all ones (DV=4 exact) — unused
    const int*   check_adj  = (const int*)d_in[4];
    const float* check_mask = (const float*)d_in[5];
    // d_in[6] var_idx — implicit in posw; unused
    // d_in[7] pcm_dense — unused
    float* out = (float*)d_out;
    int*   ws  = (int*)d_ws;    // needs ~295 KB

    const int B      = in_sizes[0] / MC;      // 256
    const int max_dc = in_sizes[4] / MC;

    setup_all<<<1, BLOCK, 0, stream>>>(check_mask, check_adj, var_adj, max_dc, ws);
    bp_decode<<<B, BLOCK, 0, stream>>>(syndrome, llr, ws, out, B);
}

// Round 7
// 407.376 us; speedup vs baseline: 2.4444x; 2.4444x over previous
//
#include <hip/hip_runtime.h>
#include <math.h>

// Min-sum BP LDPC decoder, LDS-resident messages in VAR-ORDER layout.
// msg[4v..4v+3] = var v's 4 edge messages -> var phase & epilogue are aligned
// b128 LDS ops (conflict-free). Check phase addresses its edges via positions
// packed 2x16b into NAMED registers (int4 for d<=8 bands, 7-int struct for
// d<=14 bands) -- no indexed arrays anywhere in the check path, so SROA
// cannot demote them to scratch (the R3-R6 failure mode: VGPR pinned at 64,
// arrays in scratch, 100-450 MB of spill writes).
//
// R7 design:
//  - check k = t + k*BLOCK over degree-sorted checks: lanes consecutive ->
//    wave-uniform degree; each thread gets one check per quartile -> balanced.
//  - k=0,1 bands have d<=8 (Poisson(8) CDF: sorted idx<2048 => d<=8): int4.
//  - k=2,3 bands d<=14 via 7-int struct; d>14 (~75 checks) -> global fallback.
//  - per-edge code via macros with named x0..x13 floats (no arrays).
//  - epilogue parity via global posbs reads (outside hot loop).
//  - 2 barriers/iter (edge-0 owner publishes reference's pad during var phase).

#define BLOCK 1024
#define NV    8192          // N variables
#define MC    4096          // M checks
#define NE    32768         // E edges (N * DV, DV=4)
#define VPT   (NV / BLOCK)  // 8 vars per thread
#define CPT   (MC / BLOCK)  // 4 checks per thread
#define NITER 10
#define ALPHA 0.8f
#define CLAMP 20.0f
#define BIGF  3.0e38f

// ws layout (ints):
#define WS_POSW  0                       // [NE]   word pos of edge e (orig id)
#define WS_ST2   (NE)                    // [MC+1] edge prefix, sorted order
#define WS_SC    (NE + MC + 64)          // [MC]   orig check idx per sorted slot
#define WS_POSBS (NE + 2*MC + 128)       // [NE]   positions, sorted-contiguous
#define WS_PAD   (2*NE + 2*MC + 128)     // [1]    word pos of edge 0

// ---------------- setup: sort checks by degree, build posbs ----------------
__global__ __launch_bounds__(BLOCK)
void setup_all(const float* __restrict__ check_mask,
               const int*   __restrict__ check_adj,
               const int*   __restrict__ var_adj,
               int max_dc, int* __restrict__ ws)
{
    __shared__ int ldeg[MC], lcst[MC], lso[MC];   // 48 KB
    __shared__ int part[BLOCK];
    __shared__ int hist[64], hbase[64];
    const int t = threadIdx.x;
    if (t < 64) hist[t] = 0;

    // posw: var v's j-th edge (ascending edge id = var_adj row order) lives at
    // var-order word 4v+j. Slot order preserves the reference's f32 sum order.
#pragma unroll
    for (int k = 0; k < VPT; ++k) {
        const int v = t + k * BLOCK;
        const int4 a = ((const int4*)var_adj)[v];
        ws[WS_POSW + a.x] = 4 * v + 0;
        ws[WS_POSW + a.y] = 4 * v + 1;
        ws[WS_POSW + a.z] = 4 * v + 2;
        ws[WS_POSW + a.w] = 4 * v + 3;
    }
    __syncthreads();
#pragma unroll
    for (int k = 0; k < CPT; ++k) {
        const int c = t + k * BLOCK;
        int d = 0;
        for (int j = 0; j < max_dc; ++j)
            d += (check_mask[(size_t)c * max_dc + j] != 0.0f) ? 1 : 0;
        ldeg[c] = d;
        lcst[c] = check_adj[(size_t)c * max_dc];  // row start (edges check-sorted)
        atomicAdd(&hist[d & 63], 1);
    }
    __syncthreads();
    if (t == 0) { int s = 0; for (int i = 0; i < 64; ++i) { hbase[i] = s; s += hist[i]; } }
    __syncthreads();
#pragma unroll
    for (int k = 0; k < CPT; ++k) {
        const int c = t + k * BLOCK;
        const int pos = atomicAdd(&hbase[ldeg[c] & 63], 1);
        lso[pos] = c;
    }
    __syncthreads();

    // prefix-sum sorted degrees (4 consecutive per thread + block scan)
    int sd[CPT]; int mysum = 0;
#pragma unroll
    for (int k = 0; k < CPT; ++k) { sd[k] = ldeg[lso[CPT * t + k]]; mysum += sd[k]; }
    part[t] = mysum; __syncthreads();
    for (int ofs = 1; ofs < BLOCK; ofs <<= 1) {
        const int v = (t >= ofs) ? part[t - ofs] : 0; __syncthreads();
        part[t] += v; __syncthreads();
    }
    int run = part[t] - mysum;   // exclusive prefix

#pragma unroll
    for (int k = 0; k < CPT; ++k) {
        const int i = CPT * t + k;
        const int c = lso[i];
        ws[WS_ST2 + i] = run;
        ws[WS_SC + i]  = c;
        const int cst = lcst[c];
        for (int j = 0; j < sd[k]; ++j)
            ws[WS_POSBS + run + j] = ws[WS_POSW + cst + j];
        run += sd[k];
    }
    if (t == BLOCK - 1) ws[WS_ST2 + MC] = run;
    if (t == 0)         ws[WS_PAD] = ws[WS_POSW + 0];
}

// ---------------- position packing (named registers only) ----------------
struct PKS { int4 a; int bx, by, cz; };   // 14 16-bit positions

__device__ __forceinline__ int pkpair(const int* __restrict__ p, int b, int d, int j) {
    const int lo = (j     < d) ? p[b + j]     : 0;
    const int hi = (j + 1 < d) ? p[b + j + 1] : 0;
    return (lo & 0xffff) | (hi << 16);
}
__device__ __forceinline__ int4 pk4(const int* __restrict__ p, int b, int d) {
    int4 r;
    r.x = pkpair(p, b, d, 0); r.y = pkpair(p, b, d, 2);
    r.z = pkpair(p, b, d, 4); r.w = pkpair(p, b, d, 6);
    return r;
}
__device__ __forceinline__ PKS pk7(const int* __restrict__ p, int b, int d) {
    PKS r;
    r.a  = pk4(p, b, d);
    r.bx = pkpair(p, b, d, 8); r.by = pkpair(p, b, d, 10); r.cz = pkpair(p, b, d, 12);
    return r;
}

// ---------------- per-edge code (named scalars, no arrays) ----------------
#define EDGE_READ(j)  float x##j = BIGF; if (d > j) x##j = msg[q##j];
#define EDGE_MIN(j)   { par ^= __float_as_uint(x##j); const float aa = fabsf(x##j); \
                        min2 = fminf(min2, fmaxf(min1, aa)); min1 = fminf(min1, aa); }
#define EDGE_WRITE(j) if (d > j) { const float aa = fabsf(x##j); \
                        const float mm = (fabsf(aa - min1) < 1e-9f) ? min2 : min1; \
                        msg[q##j] = __uint_as_float(__float_as_uint(ALPHA * mm) ^ \
                                    (tb ^ (__float_as_uint(x##j) & 0x80000000u))); }

// d <= 8: positions in one int4
__device__ __forceinline__ void check8(float* __restrict__ msg, int4 pa,
                                       int d, unsigned sb31, float pad)
{
    const int q0 = pa.x & 0xffff, q1 = (pa.x >> 16) & 0xffff;
    const int q2 = pa.y & 0xffff, q3 = (pa.y >> 16) & 0xffff;
    const int q4 = pa.z & 0xffff, q5 = (pa.z >> 16) & 0xffff;
    const int q6 = pa.w & 0xffff, q7 = (pa.w >> 16) & 0xffff;
    EDGE_READ(0) EDGE_READ(1) EDGE_READ(2) EDGE_READ(3)
    EDGE_READ(4) EDGE_READ(5) EDGE_READ(6) EDGE_READ(7)
    unsigned par = 0; float min1 = pad, min2 = pad;
    EDGE_MIN(0) EDGE_MIN(1) EDGE_MIN(2) EDGE_MIN(3)
    EDGE_MIN(4) EDGE_MIN(5) EDGE_MIN(6) EDGE_MIN(7)
    const unsigned tb = sb31 ^ (par & 0x80000000u);
    EDGE_WRITE(0) EDGE_WRITE(1) EDGE_WRITE(2) EDGE_WRITE(3)
    EDGE_WRITE(4) EDGE_WRITE(5) EDGE_WRITE(6) EDGE_WRITE(7)
}

// d <= 14: positions in PKS
__device__ __forceinline__ void check14(float* __restrict__ msg, PKS p,
                                        int d, unsigned sb31, float pad)
{
    const int q0  = p.a.x & 0xffff, q1  = (p.a.x >> 16) & 0xffff;
    const int q2  = p.a.y & 0xffff, q3  = (p.a.y >> 16) & 0xffff;
    const int q4  = p.a.z & 0xffff, q5  = (p.a.z >> 16) & 0xffff;
    const int q6  = p.a.w & 0xffff, q7  = (p.a.w >> 16) & 0xffff;
    const int q8  = p.bx  & 0xffff, q9  = (p.bx  >> 16) & 0xffff;
    const int q10 = p.by  & 0xffff, q11 = (p.by  >> 16) & 0xffff;
    const int q12 = p.cz  & 0xffff, q13 = (p.cz  >> 16) & 0xffff;
    EDGE_READ(0) EDGE_READ(1) EDGE_READ(2)  EDGE_READ(3)
    EDGE_READ(4) EDGE_READ(5) EDGE_READ(6)  EDGE_READ(7)
    EDGE_READ(8) EDGE_READ(9) EDGE_READ(10) EDGE_READ(11)
    EDGE_READ(12) EDGE_READ(13)
    unsigned par = 0; float min1 = pad, min2 = pad;
    EDGE_MIN(0) EDGE_MIN(1) EDGE_MIN(2)  EDGE_MIN(3)
    EDGE_MIN(4) EDGE_MIN(5) EDGE_MIN(6)  EDGE_MIN(7)
    EDGE_MIN(8) EDGE_MIN(9) EDGE_MIN(10) EDGE_MIN(11)
    EDGE_MIN(12) EDGE_MIN(13)
    const unsigned tb = sb31 ^ (par & 0x80000000u);
    EDGE_WRITE(0) EDGE_WRITE(1) EDGE_WRITE(2)  EDGE_WRITE(3)
    EDGE_WRITE(4) EDGE_WRITE(5) EDGE_WRITE(6)  EDGE_WRITE(7)
    EDGE_WRITE(8) EDGE_WRITE(9) EDGE_WRITE(10) EDGE_WRITE(11)
    EDGE_WRITE(12) EDGE_WRITE(13)
}

// d > 14 (~75 checks): positions from global posbs (contiguous, L1/L2-hot).
// Runtime loops, no local arrays (proven no-spill form).
__device__ __forceinline__ void check_glb(float* __restrict__ msg,
                                          const int* __restrict__ pp, int d,
                                          unsigned sb31, float pad)
{
    float min1 = pad, min2 = pad;
    unsigned par = 0;
    for (int j = 0; j < d; ++j) {
        const float xx = msg[pp[j]];
        par ^= __float_as_uint(xx);
        const float a = fabsf(xx);
        min2 = fminf(min2, fmaxf(min1, a));
        min1 = fminf(min1, a);
    }
    const unsigned tb = sb31 ^ (par & 0x80000000u);
    for (int j = 0; j < d; ++j) {
        const int   p  = pp[j];
        const float xx = msg[p];
        const float a  = fabsf(xx);
        const float m  = (fabsf(a - min1) < 1e-9f) ? min2 : min1;
        const unsigned sm = tb ^ (__float_as_uint(xx) & 0x80000000u);
        msg[p] = __uint_as_float(__float_as_uint(ALPHA * m) ^ sm);
    }
}

__global__ __launch_bounds__(BLOCK)
void bp_decode(const float* __restrict__ syndrome,    // (B, M)
               const float* __restrict__ llr_g,       // (B, N)
               const int*   __restrict__ ws,
               float* __restrict__ out,               // marginals | hard | converged
               int B)
{
    __shared__ float msg[NE];   // 128 KB, var-order; ctv <-> vtc in place
    __shared__ float sh_pad;
    __shared__ int   mism;

    const int b = blockIdx.x;
    const int t = threadIdx.x;

#pragma unroll
    for (int k = 0; k < VPT; ++k)                     // ctv0 = 0
        ((float4*)msg)[t + k * BLOCK] = make_float4(0.f, 0.f, 0.f, 0.f);

    float llr[VPT];
#pragma unroll
    for (int k = 0; k < VPT; ++k)
        llr[k] = llr_g[(size_t)b * NV + t + k * BLOCK];

    const int pos0 = ws[WS_PAD];         // edge 0's word position
    const int v0   = pos0 >> 2;
    const int s0   = pos0 & 3;

    const int* __restrict__ posbs = ws + WS_POSBS;

    int dsb[CPT], stv[CPT];              // (deg<<1)|sb ; sorted edge base
#pragma unroll
    for (int k = 0; k < CPT; ++k) {
        const int i = t + k * BLOCK;     // one check per degree quartile
        const int s = ws[WS_ST2 + i];
        const int e = ws[WS_ST2 + i + 1];
        const int c = ws[WS_SC + i];
        stv[k] = s;
        const int sb = (syndrome[(size_t)b * MC + c] > 0.5f) ? 1 : 0;
        dsb[k] = ((e - s) << 1) | sb;
    }
    // positions -> named registers (int4 for low bands, PKS for high bands)
    const int4 pa0 = pk4(posbs, stv[0], dsb[0] >> 1);
    const int4 pa1 = pk4(posbs, stv[1], dsb[1] >> 1);
    const PKS  p2  = pk7(posbs, stv[2], dsb[2] >> 1);
    const PKS  p3  = pk7(posbs, stv[3], dsb[3] >> 1);
    __syncthreads();

    for (int it = 0; it < NITER; ++it) {
        // ---- variable phase: pairs of b128 (reads batched before writes) ----
#pragma unroll
        for (int k = 0; k < VPT; k += 2) {
            const float4 fA = ((const float4*)msg)[t + k * BLOCK];
            const float4 fB = ((const float4*)msg)[t + (k + 1) * BLOCK];
            {
                const float base = llr[k] + (((fA.x + fA.y) + fA.z) + fA.w);
                float4 o;
                o.x = fminf(fmaxf(base - fA.x, -CLAMP), CLAMP);
                o.y = fminf(fmaxf(base - fA.y, -CLAMP), CLAMP);
                o.z = fminf(fmaxf(base - fA.z, -CLAMP), CLAMP);
                o.w = fminf(fmaxf(base - fA.w, -CLAMP), CLAMP);
                if (t + k * BLOCK == v0) {   // reference pad = |vtc[edge0]| + 1e6
                    float vt = o.x;
                    if (s0 == 1) vt = o.y; else if (s0 == 2) vt = o.z; else if (s0 == 3) vt = o.w;
                    sh_pad = fabsf(vt) + 1.0e6f;
                }
                ((float4*)msg)[t + k * BLOCK] = o;
            }
            {
                const float base = llr[k + 1] + (((fB.x + fB.y) + fB.z) + fB.w);
                float4 o;
                o.x = fminf(fmaxf(base - fB.x, -CLAMP), CLAMP);
                o.y = fminf(fmaxf(base - fB.y, -CLAMP), CLAMP);
                o.z = fminf(fmaxf(base - fB.z, -CLAMP), CLAMP);
                o.w = fminf(fmaxf(base - fB.w, -CLAMP), CLAMP);
                if (t + (k + 1) * BLOCK == v0) {
                    float vt = o.x;
                    if (s0 == 1) vt = o.y; else if (s0 == 2) vt = o.z; else if (s0 == 3) vt = o.w;
                    sh_pad = fabsf(vt) + 1.0e6f;
                }
                ((float4*)msg)[t + (k + 1) * BLOCK] = o;
            }
        }
        __syncthreads();
        const float pad = sh_pad;

        // ---- check phase: named-register positions, wave-uniform arms ----
        {
            const int d = dsb[0] >> 1; const unsigned sb = (dsb[0] & 1) ? 0x80000000u : 0u;
            if (d <= 8) check8(msg, pa0, d, sb, pad);
            else        check_glb(msg, posbs + stv[0], d, sb, pad);
        }
        {
            const int d = dsb[1] >> 1; const unsigned sb = (dsb[1] & 1) ? 0x80000000u : 0u;
            if (d <= 8) check8(msg, pa1, d, sb, pad);
            else        check_glb(msg, posbs + stv[1], d, sb, pad);
        }
        {
            const int d = dsb[2] >> 1; const unsigned sb = (dsb[2] & 1) ? 0x80000000u : 0u;
            if (d <= 8)       check8(msg, p2.a, d, sb, pad);
            else if (d <= 14) check14(msg, p2, d, sb, pad);
            else              check_glb(msg, posbs + stv[2], d, sb, pad);
        }
        {
            const int d = dsb[3] >> 1; const unsigned sb = (dsb[3] & 1) ? 0x80000000u : 0u;
            if (d <= 8)       check8(msg, p3.a, d, sb, pad);
            else if (d <= 14) check14(msg, p3, d, sb, pad);
            else              check_glb(msg, posbs + stv[3], d, sb, pad);
        }
        __syncthreads();
    }

    // ---- finale: marginals, hard decisions, convergence ----
    float marg[VPT], hard[VPT];
#pragma unroll
    for (int k = 0; k < VPT; k += 2) {
        const float4 fA = ((const float4*)msg)[t + k * BLOCK];
        const float4 fB = ((const float4*)msg)[t + (k + 1) * BLOCK];
        {
            const float tl = llr[k] + (((fA.x + fA.y) + fA.z) + fA.w);
            const float mg = 1.0f / (1.0f + expf(tl));   // sigmoid(-tl)
            marg[k] = mg; hard[k] = (mg > 0.5f) ? 1.0f : 0.0f;
        }
        {
            const float tl = llr[k + 1] + (((fB.x + fB.y) + fB.z) + fB.w);
            const float mg = 1.0f / (1.0f + expf(tl));
            marg[k + 1] = mg; hard[k + 1] = (mg > 0.5f) ? 1.0f : 0.0f;
        }
    }
    if (t == 0) mism = 0;
    __syncthreads();   // all ctv reads done; mism initialized

    const size_t BN = (size_t)B * NV;
#pragma unroll
    for (int k = 0; k < VPT; ++k) {
        const int v = t + k * BLOCK;
        out[(size_t)b * NV + v]      = marg[k];        // output 0: marginals
        out[BN + (size_t)b * NV + v] = hard[k];        // output 1: hard_decision
        const float h = hard[k];
        ((float4*)msg)[v] = make_float4(h, h, h, h);   // hard bit to all slots
    }
    __syncthreads();

    // syn_hat parity per check via global posbs (outside hot loop; L2-hot)
#pragma unroll
    for (int k = 0; k < CPT; ++k) {
        const int d = dsb[k] >> 1;
        const int* __restrict__ pp = posbs + stv[k];
        int par = 0;
        for (int j = 0; j < d; ++j)
            par ^= (msg[pp[j]] != 0.0f) ? 1 : 0;
        if (par != (dsb[k] & 1)) mism = 1;   // benign race: all writers store 1
    }
    __syncthreads();
    if (t == 0) out[2 * BN + b] = mism ? 0.0f : 1.0f;  // output 2: converged
}

extern "C" void kernel_launch(void* const* d_in, const int* in_sizes, int n_in,
                              void* d_out, int out_size, void* d_ws, size_t ws_size,
                              hipStream_t stream) {
    const float* syndrome   = (const float*)d_in[0];
    const float* llr        = (const float*)d_in[1];
    const int*   var_adj    = (const int*)d_in[2];
    // d_in[3] var_adj_mask: all ones (DV=4 exact) — unused
    const int*   check_adj  = (const int*)d_in[4];
    const float* check_mask = (const float*)d_in[5];
    // d_in[6] var_idx — implicit in posw; unused
    // d_in[7] pcm_dense — unused
    float* out = (float*)d_out;
    int*   ws  = (int*)d_ws;    // needs ~295 KB

    const int B      = in_sizes[0] / MC;      // 256
    const int max_dc = in_sizes[4] / MC;

    setup_all<<<1, BLOCK, 0, stream>>>(check_mask, check_adj, var_adj, max_dc, ws);
    bp_decode<<<B, BLOCK, 0, stream>>>(syndrome, llr, ws, out, B);
}